// Round 3
// baseline (712.353 us; speedup 1.0000x reference)
//
#include <hip/hip_runtime.h>

typedef unsigned short u16;
typedef __attribute__((ext_vector_type(8))) short short8;
typedef __attribute__((ext_vector_type(4))) float float4v;

#define MFMA_BF16(a, b, c) __builtin_amdgcn_mfma_f32_16x16x32_bf16((a), (b), (c), 0, 0, 0)

#define B_ 4
#define S_ 2048
#define D_ 1024
#define H_ 8
#define DH_ 128
#define DFF_ 4096
#define EPS_ 1e-5f
#define ROWS_ (B_ * S_)   // 8192
#define CSCALE_ 0.12751672939502f  // (1/sqrt(128)) * log2(e), folded into Q

__device__ __forceinline__ u16 f2bf(float f) {
  union { float f; unsigned u; } x; x.f = f;
  unsigned r = x.u + 0x7fffu + ((x.u >> 16) & 1u);
  return (u16)(r >> 16);
}

typedef __attribute__((address_space(1))) const unsigned int guint;
typedef __attribute__((address_space(3))) unsigned int luint;
__device__ __forceinline__ void gl2lds16(const u16* g, u16* l) {
  // each lane: 16B from its own g -> wave-uniform lds base + lane*16
  __builtin_amdgcn_global_load_lds((guint*)g, (luint*)l, 16, 0, 0);
}

// ---------------- cast fp32 -> bf16 (layout preserved) ----------------
__global__ void cast_bf16_kernel(const float* __restrict__ in, u16* __restrict__ out, int n4) {
  int i = blockIdx.x * blockDim.x + threadIdx.x;
  int stride = gridDim.x * blockDim.x;
  for (; i < n4; i += stride) {
    float4 v = ((const float4*)in)[i];
    ushort4 u;
    u.x = f2bf(v.x); u.y = f2bf(v.y); u.z = f2bf(v.z); u.w = f2bf(v.w);
    ((ushort4*)out)[i] = u;
  }
}

// ---------- cast+transpose fp32 [K][N] -> bf16 [N][K] (weights) ----------
__global__ void transpose_cast_kernel(const float* __restrict__ in, u16* __restrict__ out,
                                      int K, int N) {
  __shared__ float t[32][33];
  int k0 = blockIdx.x * 32, n0 = blockIdx.y * 32;
  int tx = threadIdx.x & 31, ty = threadIdx.x >> 5;  // 32x8 threads
  #pragma unroll
  for (int i = 0; i < 4; ++i)
    t[ty + 8 * i][tx] = in[(size_t)(k0 + ty + 8 * i) * N + n0 + tx];
  __syncthreads();
  #pragma unroll
  for (int i = 0; i < 4; ++i)
    out[(size_t)(n0 + ty + 8 * i) * K + k0 + tx] = f2bf(t[tx][ty + 8 * i]);
}

// ------- transpose V bf16 [bh][S][DH] -> [bh][DH][S] (for PV B-operand) -------
__global__ void transpose_v_kernel(const u16* __restrict__ in, u16* __restrict__ out) {
  __shared__ u16 t[32][33];
  int s0 = blockIdx.x * 32, d0 = blockIdx.y * 32, bh = blockIdx.z;
  const u16* src = in + (size_t)bh * S_ * DH_;
  u16* dst = out + (size_t)bh * DH_ * S_;
  int tx = threadIdx.x & 31, ty = threadIdx.x >> 5;
  #pragma unroll
  for (int i = 0; i < 4; ++i)
    t[ty + 8 * i][tx] = src[(size_t)(s0 + ty + 8 * i) * DH_ + d0 + tx];
  __syncthreads();
  #pragma unroll
  for (int i = 0; i < 4; ++i)
    dst[(size_t)(d0 + ty + 8 * i) * S_ + s0 + tx] = t[tx][ty + 8 * i];
}

// -------- bf16 MFMA GEMM v3 (flatmm-style): C[M,N] = A[M,K] @ Bt[N,K]^T --------
// A fragments stream global->VGPR (register double-buffer, barrier-free);
// B tiles double-buffered in LDS via global_load_lds, ONE barrier per K-iter:
//   iter i: barrier; DMA tile i+1 -> buf[(i+1)&1]; ds_read buf[i&1]; MFMA.
// The DMA issued at iter i drains at barrier_{i+1} -> a full MFMA span in flight.
// MODE 0: scatter q/k/v bf16 ([b,h,s,dh], q pre-scaled by CSCALE_);
// MODE 1: +resid, fp32 store; MODE 2: +bias, relu, bf16; MODE 3: +bias+resid, fp32.
template <int MODE, int KT>
__global__ __launch_bounds__(256) void gemm_kernel(
    const u16* __restrict__ A, const u16* __restrict__ Bt,
    const int M, const int N,
    float* __restrict__ outF, u16* __restrict__ outH, const float* __restrict__ bias,
    const float* __restrict__ resid,
    u16* __restrict__ qo, u16* __restrict__ ko, u16* __restrict__ vo) {
  __shared__ u16 Bs[2][128][32];  // 16 KB, no pad (gl2lds lane-contiguous dest)
  const int tid = threadIdx.x;
  const int lane = tid & 63, wave = tid >> 6;
  const int quad = lane >> 4, r16 = lane & 15;
  const int wm = (wave >> 1) * 64, wn = (wave & 1) * 64;
  const int m0 = blockIdx.x * 128, n0 = blockIdx.y * 128;
  const int K = KT, niter = KT >> 5;

  float4v acc[4][4];
  #pragma unroll
  for (int i = 0; i < 4; ++i)
    #pragma unroll
    for (int j = 0; j < 4; ++j) acc[i][j] = (float4v)0.0f;

  // B staging: wave w covers rows [32w, 32w+32) as 2 chunks of 16 rows;
  // lane -> row lane/4, 16B segment lane%4.
  const int srow = lane >> 2, sseg = lane & 3;
  const u16* Bg0 = Bt + (size_t)(n0 + wave * 32 + srow) * K + sseg * 8;
  const u16* Bg1 = Bg0 + (size_t)16 * K;
  u16* Bl0 = &Bs[0][wave * 32][0];
  u16* Bl1 = &Bs[0][wave * 32 + 16][0];
  const size_t bufStep = (size_t)128 * 32;  // u16 elements per buffer

  // A fragment pointers: lane holds A[m = wm+t*16+r16][k = quad*8 + j]
  const u16* Ap[4];
  #pragma unroll
  for (int t = 0; t < 4; ++t)
    Ap[t] = A + (size_t)(m0 + wm + t * 16 + r16) * K + quad * 8;

  // prologue: DMA tile 0 -> buf 0; A frags for k0=0 -> registers
  gl2lds16(Bg0, Bl0);
  gl2lds16(Bg1, Bl1);
  short8 a_cur[4], a_next[4];
  #pragma unroll
  for (int t = 0; t < 4; ++t) a_cur[t] = *(const short8*)(Ap[t]);

  #pragma unroll 4
  for (int i = 0; i < niter; ++i) {
    __syncthreads();  // drains DMA for buf[i&1]; protects buf[(i+1)&1] overwrite
    if (i + 1 < niter) {
      const int k1 = (i + 1) << 5;
      const size_t bo = ((i + 1) & 1) ? bufStep : 0;
      gl2lds16(Bg0 + k1, Bl0 + bo);
      gl2lds16(Bg1 + k1, Bl1 + bo);
      #pragma unroll
      for (int t = 0; t < 4; ++t) a_next[t] = *(const short8*)(Ap[t] + k1);
    }
    short8 bf[4];
    #pragma unroll
    for (int t = 0; t < 4; ++t)
      bf[t] = *(const short8*)&Bs[i & 1][wn + t * 16 + r16][quad * 8];
    #pragma unroll
    for (int ii = 0; ii < 4; ++ii)
      #pragma unroll
      for (int j = 0; j < 4; ++j) acc[ii][j] = MFMA_BF16(a_cur[ii], bf[j], acc[ii][j]);
    #pragma unroll
    for (int t = 0; t < 4; ++t) a_cur[t] = a_next[t];
  }

  // epilogue: D row = quad*4+reg, col = r16 within each 16x16 tile
  #pragma unroll
  for (int i = 0; i < 4; ++i) {
    const int rowb = m0 + wm + i * 16 + quad * 4;
    #pragma unroll
    for (int j = 0; j < 4; ++j) {
      const int col = n0 + wn + j * 16 + r16;
      #pragma unroll
      for (int rg = 0; rg < 4; ++rg) {
        float val = acc[i][j][rg];
        const int r = rowb + rg;
        if (MODE == 0) {
          const int part = col >> 10, cc = col & 1023;
          const int h = cc >> 7, dh = cc & 127;
          const int b = r >> 11, s = r & 2047;
          u16* dst = (part == 0) ? qo : (part == 1) ? ko : vo;
          if (part == 0) val *= CSCALE_;  // fold softmax scale*log2e into Q
          dst[((size_t)(b * H_ + h) * S_ + s) * DH_ + dh] = f2bf(val);
        } else if (MODE == 1) {
          val += resid[(size_t)r * N + col];  // + src residual
          outF[(size_t)r * N + col] = val;
        } else if (MODE == 2) {
          val += bias[col];
          val = fmaxf(val, 0.0f);
          outH[(size_t)r * N + col] = f2bf(val);
        } else {
          val += bias[col] + resid[(size_t)r * N + col];  // + xf residual
          outF[(size_t)r * N + col] = val;
        }
      }
    }
  }
}

// ---------------- flash causal attention (S^T formulation) ----------------
__global__ __launch_bounds__(256) void attn_kernel(
    const u16* __restrict__ Q, const u16* __restrict__ Kg,
    const u16* __restrict__ Vtg, u16* __restrict__ O) {
  __shared__ u16 Ks[64][136];     // [key][d]
  __shared__ u16 Vt[128][72];     // [d][key]
  __shared__ u16 Pw[4][16][72];   // per-wave P [q][key]
  const int tid = threadIdx.x;
  const int lane = tid & 63, wave = tid >> 6;
  const int quad = lane >> 4, r16 = lane & 15;
  const int pairIdx = blockIdx.x;  // 0..15
  const int bh = blockIdx.y;       // 0..31
  const size_t base = (size_t)bh * S_ * DH_;
  const size_t vtb = (size_t)bh * DH_ * S_;
  const int b = bh >> 3, h = bh & 7;

  const u16* kg0 = Kg + base + (size_t)(tid >> 4) * DH_ + (tid & 15) * 8;
  u16* ksl = &Ks[tid >> 4][(tid & 15) * 8];
  const u16* vg0 = Vtg + vtb + (size_t)(tid >> 3) * S_ + (tid & 7) * 8;
  u16* vtl = &Vt[tid >> 3][(tid & 7) * 8];

  for (int half = 0; half < 2; ++half) {
    const int qb = (half == 0) ? pairIdx : 31 - pairIdx;
    const int qr = qb * 64 + wave * 16 + r16;

    short8 aq[4];
    #pragma unroll
    for (int ks = 0; ks < 4; ++ks)
      aq[ks] = *(const short8*)(Q + base + (size_t)qr * DH_ + ks * 32 + quad * 8);

    float4v acco[8];
    #pragma unroll
    for (int i = 0; i < 8; ++i) acco[i] = (float4v)0.0f;
    float m_q = -1e30f, l_q = 0.0f;

    for (int kb = 0; kb <= qb; ++kb) {
      __syncthreads();
      #pragma unroll
      for (int i = 0; i < 4; ++i)
        *(short8*)(ksl + i * 16 * 136) =
            *(const short8*)(kg0 + (size_t)(kb * 64 + i * 16) * DH_);
      #pragma unroll
      for (int i = 0; i < 4; ++i)
        *(short8*)(vtl + i * 32 * 72) =
            *(const short8*)(vg0 + (size_t)i * 32 * S_ + kb * 64);
      __syncthreads();

      float4v accs[4];
      #pragma unroll
      for (int t = 0; t < 4; ++t) accs[t] = (float4v)0.0f;
      #pragma unroll
      for (int ks = 0; ks < 4; ++ks) {
        #pragma unroll
        for (int t = 0; t < 4; ++t) {
          short8 ak = *(const short8*)&Ks[t * 16 + r16][ks * 32 + quad * 8];
          accs[t] = MFMA_BF16(ak, aq[ks], accs[t]);
        }
      }
      if (kb == qb) {
        #pragma unroll
        for (int t = 0; t < 4; ++t)
          #pragma unroll
          for (int rg = 0; rg < 4; ++rg) {
            int kc = kb * 64 + t * 16 + quad * 4 + rg;
            if (kc > qr) accs[t][rg] = -1e30f;
          }
      }
      float mv = accs[0][0];
      #pragma unroll
      for (int t = 0; t < 4; ++t)
        #pragma unroll
        for (int rg = 0; rg < 4; ++rg) mv = fmaxf(mv, accs[t][rg]);
      mv = fmaxf(mv, __shfl_xor(mv, 16));
      mv = fmaxf(mv, __shfl_xor(mv, 32));
      const float mnew = fmaxf(m_q, mv);
      const float alpha = __builtin_amdgcn_exp2f(m_q - mnew);
      float s0 = 0.0f;
      #pragma unroll
      for (int t = 0; t < 4; ++t)
        #pragma unroll
        for (int rg = 0; rg < 4; ++rg) {
          float p = __builtin_amdgcn_exp2f(accs[t][rg] - mnew);
          accs[t][rg] = p;
          s0 += p;
        }
      s0 += __shfl_xor(s0, 16);
      s0 += __shfl_xor(s0, 32);
      l_q = l_q * alpha + s0;
      m_q = mnew;

      #pragma unroll
      for (int t = 0; t < 4; ++t) {
        union { float f; unsigned u; } c0, c1, c2, c3;
        c0.f = accs[t][0]; c1.f = accs[t][1]; c2.f = accs[t][2]; c3.f = accs[t][3];
        uint2 pk;
        pk.x = ((c0.u + 0x8000u) >> 16) | ((c1.u + 0x8000u) & 0xffff0000u);
        pk.y = ((c2.u + 0x8000u) >> 16) | ((c3.u + 0x8000u) & 0xffff0000u);
        *(uint2*)&Pw[wave][r16][t * 16 + quad * 4] = pk;
      }
      float al[4];
      #pragma unroll
      for (int rg = 0; rg < 4; ++rg) al[rg] = __shfl(alpha, quad * 4 + rg);
      #pragma unroll
      for (int nt = 0; nt < 8; ++nt)
        #pragma unroll
        for (int rg = 0; rg < 4; ++rg) acco[nt][rg] *= al[rg];
      asm volatile("s_waitcnt lgkmcnt(0)" ::: "memory");
      #pragma unroll
      for (int ks2 = 0; ks2 < 2; ++ks2) {
        short8 ap = *(const short8*)&Pw[wave][r16][ks2 * 32 + quad * 8];
        #pragma unroll
        for (int nt = 0; nt < 8; ++nt) {
          short8 bv = *(const short8*)&Vt[nt * 16 + r16][ks2 * 32 + quad * 8];
          acco[nt] = MFMA_BF16(ap, bv, acco[nt]);
        }
      }
    }

    float lr[4];
    #pragma unroll
    for (int rg = 0; rg < 4; ++rg) lr[rg] = __shfl(l_q, quad * 4 + rg);
    const int sbase = qb * 64 + wave * 16 + quad * 4;
    #pragma unroll
    for (int nt = 0; nt < 8; ++nt)
      #pragma unroll
      for (int rg = 0; rg < 4; ++rg) {
        float val = acco[nt][rg] / lr[rg];
        O[((size_t)(b * S_ + sbase + rg)) * D_ + h * DH_ + nt * 16 + r16] = f2bf(val);
      }
  }
}

// ---------------- layernorm: y = LN(a [+ res]) * g + be ----------------
__global__ __launch_bounds__(256) void ln_kernel(
    const float* __restrict__ a, const float* __restrict__ res,
    const float* __restrict__ g, const float* __restrict__ be,
    float* __restrict__ xf, u16* __restrict__ xb) {
  __shared__ float red[8];
  const int row = blockIdx.x, tid = threadIdx.x;
  float4 v = ((const float4*)(a + (size_t)row * D_))[tid];
  if (res) {
    const float4 vr = ((const float4*)(res + (size_t)row * D_))[tid];
    v.x += vr.x; v.y += vr.y; v.z += vr.z; v.w += vr.w;
  }
  float s = v.x + v.y + v.z + v.w;
  float q = v.x * v.x + v.y * v.y + v.z * v.z + v.w * v.w;
  #pragma unroll
  for (int m = 1; m < 64; m <<= 1) {
    s += __shfl_xor(s, m);
    q += __shfl_xor(q, m);
  }
  const int wave = tid >> 6, lane = tid & 63;
  if (lane == 0) { red[wave] = s; red[4 + wave] = q; }
  __syncthreads();
  s = red[0] + red[1] + red[2] + red[3];
  q = red[4] + red[5] + red[6] + red[7];
  const float mu = s * (1.0f / D_);
  const float var = q * (1.0f / D_) - mu * mu;
  const float inv = rsqrtf(var + EPS_);
  const float4 gg = ((const float4*)g)[tid];
  const float4 bb = ((const float4*)be)[tid];
  float4 y;
  y.x = (v.x - mu) * inv * gg.x + bb.x;
  y.y = (v.y - mu) * inv * gg.y + bb.y;
  y.z = (v.z - mu) * inv * gg.z + bb.z;
  y.w = (v.w - mu) * inv * gg.w + bb.w;
  ((float4*)(xf + (size_t)row * D_))[tid] = y;
  if (xb) {
    ushort4 u;
    u.x = f2bf(y.x); u.y = f2bf(y.y); u.z = f2bf(y.z); u.w = f2bf(y.w);
    ((ushort4*)(xb + (size_t)row * D_))[tid] = u;
  }
}

extern "C" void kernel_launch(void* const* d_in, const int* in_sizes, int n_in,
                              void* d_out, int out_size, void* d_ws, size_t ws_size,
                              hipStream_t stream) {
  const float* src   = (const float*)d_in[0];
  const float* w_qkv = (const float*)d_in[1];
  const float* w_out = (const float*)d_in[2];
  const float* w1    = (const float*)d_in[3];
  const float* b1    = (const float*)d_in[4];
  const float* w2    = (const float*)d_in[5];
  const float* b2    = (const float*)d_in[6];
  const float* g1    = (const float*)d_in[7];
  const float* be1   = (const float*)d_in[8];
  const float* g2    = (const float*)d_in[9];
  const float* be2   = (const float*)d_in[10];
  float* out = (float*)d_out;

  char* ws = (char*)d_ws;
  size_t off = 0;
  auto alloc = [&](size_t bytes) -> void* {
    void* p = ws + off;
    off += (bytes + 255) & ~(size_t)255;
    return p;
  };
  u16* src_bf = (u16*)alloc((size_t)ROWS_ * D_ * 2);
  u16* wqkvT  = (u16*)alloc((size_t)3 * D_ * D_ * 2);   // [3072][1024]
  u16* woutT  = (u16*)alloc((size_t)D_ * D_ * 2);
  u16* w1T    = (u16*)alloc((size_t)DFF_ * D_ * 2);     // [4096][1024]
  u16* w2T    = (u16*)alloc((size_t)D_ * DFF_ * 2);     // [1024][4096]
  u16* qbuf   = (u16*)alloc((size_t)ROWS_ * D_ * 2);
  u16* kbuf   = (u16*)alloc((size_t)ROWS_ * D_ * 2);
  u16* vbuf   = (u16*)alloc((size_t)ROWS_ * D_ * 2);
  u16* obuf   = (u16*)alloc((size_t)ROWS_ * D_ * 2);
  u16* vT     = (u16*)alloc((size_t)ROWS_ * D_ * 2);
  float* proj = (float*)alloc((size_t)ROWS_ * D_ * 4);
  float* xf   = (float*)alloc((size_t)ROWS_ * D_ * 4);
  u16* xb     = (u16*)alloc((size_t)ROWS_ * D_ * 2);
  u16* h1     = qbuf;   // alias: q,k,v,o dead before GEMM3 writes
  float* ff   = proj;   // alias: proj dead after LN1

  cast_bf16_kernel<<<2048, 256, 0, stream>>>(src, src_bf, ROWS_ * D_ / 4);
  transpose_cast_kernel<<<dim3(D_ / 32, 3 * D_ / 32), 256, 0, stream>>>(w_qkv, wqkvT, D_, 3 * D_);
  transpose_cast_kernel<<<dim3(D_ / 32, D_ / 32), 256, 0, stream>>>(w_out, woutT, D_, D_);
  transpose_cast_kernel<<<dim3(D_ / 32, DFF_ / 32), 256, 0, stream>>>(w1, w1T, D_, DFF_);
  transpose_cast_kernel<<<dim3(DFF_ / 32, D_ / 32), 256, 0, stream>>>(w2, w2T, DFF_, D_);

  // qkv = src @ w_qkv -> q,k,v [b,h,s,dh]
  gemm_kernel<0, 1024><<<dim3(ROWS_ / 128, 3 * D_ / 128), 256, 0, stream>>>(
      src_bf, wqkvT, ROWS_, 3 * D_, nullptr, nullptr, nullptr, nullptr, qbuf, kbuf, vbuf);
  transpose_v_kernel<<<dim3(S_ / 32, DH_ / 32, B_ * H_), 256, 0, stream>>>(vbuf, vT);
  attn_kernel<<<dim3(16, B_ * H_), 256, 0, stream>>>(qbuf, kbuf, vT, obuf);
  // proj = o @ w_out + src (residual fused)
  gemm_kernel<1, 1024><<<dim3(ROWS_ / 128, D_ / 128), 256, 0, stream>>>(
      obuf, woutT, ROWS_, D_, proj, nullptr, nullptr, src, nullptr, nullptr, nullptr);
  // x = LN(proj)
  ln_kernel<<<ROWS_, 256, 0, stream>>>(proj, nullptr, g1, be1, xf, xb);
  // h1 = relu(x @ w1 + b1) (bf16)
  gemm_kernel<2, 1024><<<dim3(ROWS_ / 128, DFF_ / 128), 256, 0, stream>>>(
      xb, w1T, ROWS_, DFF_, nullptr, h1, b1, nullptr, nullptr, nullptr, nullptr);
  // ff = h1 @ w2 + b2 + xf (residual fused)
  gemm_kernel<3, 4096><<<dim3(ROWS_ / 128, D_ / 128), 256, 0, stream>>>(
      h1, w2T, ROWS_, D_, ff, nullptr, b2, xf, nullptr, nullptr, nullptr);
  // out = LN(ff)
  ln_kernel<<<ROWS_, 256, 0, stream>>>(ff, nullptr, g2, be2, out, nullptr);
}

// Round 4
// 649.097 us; speedup vs baseline: 1.0975x; 1.0975x over previous
//
#include <hip/hip_runtime.h>

typedef unsigned short u16;
typedef __attribute__((ext_vector_type(8))) short short8;
typedef __attribute__((ext_vector_type(4))) float float4v;

#define MFMA_BF16(a, b, c) __builtin_amdgcn_mfma_f32_16x16x32_bf16((a), (b), (c), 0, 0, 0)

#define B_ 4
#define S_ 2048
#define D_ 1024
#define H_ 8
#define DH_ 128
#define DFF_ 4096
#define EPS_ 1e-5f
#define ROWS_ (B_ * S_)   // 8192
#define CSCALE_ 0.12751672939502f  // (1/sqrt(128)) * log2(e), folded into Q

__device__ __forceinline__ u16 f2bf(float f) {
  union { float f; unsigned u; } x; x.f = f;
  unsigned r = x.u + 0x7fffu + ((x.u >> 16) & 1u);
  return (u16)(r >> 16);
}

// Tiled fragment-major layout: element (row, k) of a [Rows][Kdim] bf16 matrix
// lives in 128x32 tiles, each tile 4096 elems (8 KB) contiguous. A wave's MFMA
// fragment load (16 rows x 8 k per lane-quad) is then ONE contiguous 1 KB
// global_load_dwordx4 -- the flatmm trick enabling zero-LDS GEMMs.
__device__ __forceinline__ size_t tiled_off(int row, int k, int Kdim) {
  return ((size_t)(row >> 7) * (Kdim >> 5) + (k >> 5)) * 4096 +
         (size_t)((row & 127) << 5) + (k & 31);
}

// ---------------- cast fp32 row-major -> bf16 tiled (src) ----------------
__global__ void cast_tiled_kernel(const float* __restrict__ in, u16* __restrict__ out) {
  int idx = blockIdx.x * 256 + threadIdx.x;
  int g = idx * 4;
  int m = g >> 10, k = g & 1023;  // D_ = 1024
  float4 v = *(const float4*)(in + (size_t)g);
  ushort4 u;
  u.x = f2bf(v.x); u.y = f2bf(v.y); u.z = f2bf(v.z); u.w = f2bf(v.w);
  *(ushort4*)(out + tiled_off(m, k, D_)) = u;
}

// ------ cast+transpose fp32 [K][N] -> bf16 tiled [N-rows][K-cols] (weights) ------
__global__ void transpose_cast_kernel(const float* __restrict__ in, u16* __restrict__ out,
                                      int K, int N) {
  __shared__ float t[32][33];
  int k0 = blockIdx.x * 32, n0 = blockIdx.y * 32;
  int tx = threadIdx.x & 31, ty = threadIdx.x >> 5;  // 32x8 threads
  #pragma unroll
  for (int i = 0; i < 4; ++i)
    t[ty + 8 * i][tx] = in[(size_t)(k0 + ty + 8 * i) * N + n0 + tx];
  __syncthreads();
  if (threadIdx.x < 128) {
    int n = threadIdx.x >> 2, kseg = threadIdx.x & 3;
    short8 pk;
    #pragma unroll
    for (int e = 0; e < 8; ++e)
      ((u16*)&pk)[e] = f2bf(t[kseg * 8 + e][n]);
    *(short8*)(out + tiled_off(n0 + n, k0 + kseg * 8, K)) = pk;
  }
}

// ------- transpose V bf16 [bh][S][DH] -> [bh][DH][S] (for PV B-operand) -------
__global__ void transpose_v_kernel(const u16* __restrict__ in, u16* __restrict__ out) {
  __shared__ u16 t[32][33];
  int s0 = blockIdx.x * 32, d0 = blockIdx.y * 32, bh = blockIdx.z;
  const u16* src = in + (size_t)bh * S_ * DH_;
  u16* dst = out + (size_t)bh * DH_ * S_;
  int tx = threadIdx.x & 31, ty = threadIdx.x >> 5;
  #pragma unroll
  for (int i = 0; i < 4; ++i)
    t[ty + 8 * i][tx] = src[(size_t)(s0 + ty + 8 * i) * DH_ + d0 + tx];
  __syncthreads();
  #pragma unroll
  for (int i = 0; i < 4; ++i)
    dst[(size_t)(d0 + ty + 8 * i) * S_ + s0 + tx] = t[tx][ty + 8 * i];
}

// ---- bf16 MFMA GEMM v4 (flatmm): zero LDS, zero barriers, tiled operands ----
// A tiled [M/128][K/32][128][32], Bt tiled [N/128][K/32][128][32].
// Each fragment load = one coalesced 1 KB global_load_dwordx4; register
// double-buffer; compiler vmcnt pipelining overlaps loads i+1 with MFMA i.
// MODE 0: scatter q/k/v bf16 ([b,h,s,dh], q pre-scaled by CSCALE_);
// MODE 1: +resid, fp32 store; MODE 2: +bias, relu, bf16 TILED store (feeds
// GEMM3 as A); MODE 3: +bias+resid, fp32 store.
template <int MODE, int KT>
__global__ __launch_bounds__(256, 3) void gemm_kernel(
    const u16* __restrict__ A, const u16* __restrict__ Bt,
    const int M, const int N,
    float* __restrict__ outF, u16* __restrict__ outH, const float* __restrict__ bias,
    const float* __restrict__ resid,
    u16* __restrict__ qo, u16* __restrict__ ko, u16* __restrict__ vo) {
  const int tid = threadIdx.x;
  const int lane = tid & 63, wave = tid >> 6;
  const int quad = lane >> 4, r16 = lane & 15;
  const int wm = (wave >> 1) * 64, wn = (wave & 1) * 64;
  const int m0 = blockIdx.x * 128, n0 = blockIdx.y * 128;
  constexpr int niter = KT >> 5;

  float4v acc[4][4];
  #pragma unroll
  for (int i = 0; i < 4; ++i)
    #pragma unroll
    for (int j = 0; j < 4; ++j) acc[i][j] = (float4v)0.0f;

  // fragment base pointers: lane covers rows (wX + t*16 + r16), k seg quad*8
  const u16* ap[4];
  const u16* bp[4];
  #pragma unroll
  for (int t = 0; t < 4; ++t) {
    ap[t] = A + (size_t)(m0 >> 7) * niter * 4096 +
            (size_t)((wm + t * 16 + r16) << 5) + quad * 8;
    bp[t] = Bt + (size_t)(n0 >> 7) * niter * 4096 +
            (size_t)((wn + t * 16 + r16) << 5) + quad * 8;
  }

  short8 a_cur[4], b_cur[4], a_nxt[4], b_nxt[4];
  #pragma unroll
  for (int t = 0; t < 4; ++t) {
    a_cur[t] = *(const short8*)(ap[t]);
    b_cur[t] = *(const short8*)(bp[t]);
  }

  #pragma unroll 2
  for (int i = 0; i + 1 < niter; ++i) {
    const size_t o = (size_t)(i + 1) * 4096;
    #pragma unroll
    for (int t = 0; t < 4; ++t) {
      a_nxt[t] = *(const short8*)(ap[t] + o);
      b_nxt[t] = *(const short8*)(bp[t] + o);
    }
    #pragma unroll
    for (int ii = 0; ii < 4; ++ii)
      #pragma unroll
      for (int j = 0; j < 4; ++j) acc[ii][j] = MFMA_BF16(a_cur[ii], b_cur[j], acc[ii][j]);
    #pragma unroll
    for (int t = 0; t < 4; ++t) { a_cur[t] = a_nxt[t]; b_cur[t] = b_nxt[t]; }
  }
  #pragma unroll
  for (int ii = 0; ii < 4; ++ii)
    #pragma unroll
    for (int j = 0; j < 4; ++j) acc[ii][j] = MFMA_BF16(a_cur[ii], b_cur[j], acc[ii][j]);

  // epilogue: D row = quad*4+reg, col = r16 within each 16x16 tile
  #pragma unroll
  for (int i = 0; i < 4; ++i) {
    const int rowb = m0 + wm + i * 16 + quad * 4;
    #pragma unroll
    for (int j = 0; j < 4; ++j) {
      const int col = n0 + wn + j * 16 + r16;
      #pragma unroll
      for (int rg = 0; rg < 4; ++rg) {
        float val = acc[i][j][rg];
        const int r = rowb + rg;
        if (MODE == 0) {
          const int part = col >> 10, cc = col & 1023;
          const int h = cc >> 7, dh = cc & 127;
          const int b = r >> 11, s = r & 2047;
          u16* dst = (part == 0) ? qo : (part == 1) ? ko : vo;
          if (part == 0) val *= CSCALE_;  // fold softmax scale*log2e into Q
          dst[((size_t)(b * H_ + h) * S_ + s) * DH_ + dh] = f2bf(val);
        } else if (MODE == 1) {
          val += resid[(size_t)r * N + col];  // + src residual
          outF[(size_t)r * N + col] = val;
        } else if (MODE == 2) {
          val += bias[col];
          val = fmaxf(val, 0.0f);
          outH[tiled_off(r, col, N)] = f2bf(val);  // tiled: feeds GEMM3 A
        } else {
          val += bias[col] + resid[(size_t)r * N + col];  // + xf residual
          outF[(size_t)r * N + col] = val;
        }
      }
    }
  }
}

// ---------------- flash causal attention (S^T formulation) ----------------
// O written TILED (feeds proj GEMM as A operand).
__global__ __launch_bounds__(256) void attn_kernel(
    const u16* __restrict__ Q, const u16* __restrict__ Kg,
    const u16* __restrict__ Vtg, u16* __restrict__ O) {
  __shared__ u16 Ks[64][136];     // [key][d]
  __shared__ u16 Vt[128][72];     // [d][key]
  __shared__ u16 Pw[4][16][72];   // per-wave P [q][key]
  const int tid = threadIdx.x;
  const int lane = tid & 63, wave = tid >> 6;
  const int quad = lane >> 4, r16 = lane & 15;
  const int pairIdx = blockIdx.x;  // 0..15
  const int bh = blockIdx.y;       // 0..31
  const size_t base = (size_t)bh * S_ * DH_;
  const size_t vtb = (size_t)bh * DH_ * S_;
  const int b = bh >> 3, h = bh & 7;

  const u16* kg0 = Kg + base + (size_t)(tid >> 4) * DH_ + (tid & 15) * 8;
  u16* ksl = &Ks[tid >> 4][(tid & 15) * 8];
  const u16* vg0 = Vtg + vtb + (size_t)(tid >> 3) * S_ + (tid & 7) * 8;
  u16* vtl = &Vt[tid >> 3][(tid & 7) * 8];

  for (int half = 0; half < 2; ++half) {
    const int qb = (half == 0) ? pairIdx : 31 - pairIdx;
    const int qr = qb * 64 + wave * 16 + r16;

    short8 aq[4];
    #pragma unroll
    for (int ks = 0; ks < 4; ++ks)
      aq[ks] = *(const short8*)(Q + base + (size_t)qr * DH_ + ks * 32 + quad * 8);

    float4v acco[8];
    #pragma unroll
    for (int i = 0; i < 8; ++i) acco[i] = (float4v)0.0f;
    float m_q = -1e30f, l_q = 0.0f;

    for (int kb = 0; kb <= qb; ++kb) {
      __syncthreads();
      #pragma unroll
      for (int i = 0; i < 4; ++i)
        *(short8*)(ksl + i * 16 * 136) =
            *(const short8*)(kg0 + (size_t)(kb * 64 + i * 16) * DH_);
      #pragma unroll
      for (int i = 0; i < 4; ++i)
        *(short8*)(vtl + i * 32 * 72) =
            *(const short8*)(vg0 + (size_t)i * 32 * S_ + kb * 64);
      __syncthreads();

      float4v accs[4];
      #pragma unroll
      for (int t = 0; t < 4; ++t) accs[t] = (float4v)0.0f;
      #pragma unroll
      for (int ks = 0; ks < 4; ++ks) {
        #pragma unroll
        for (int t = 0; t < 4; ++t) {
          short8 ak = *(const short8*)&Ks[t * 16 + r16][ks * 32 + quad * 8];
          accs[t] = MFMA_BF16(ak, aq[ks], accs[t]);
        }
      }
      if (kb == qb) {
        #pragma unroll
        for (int t = 0; t < 4; ++t)
          #pragma unroll
          for (int rg = 0; rg < 4; ++rg) {
            int kc = kb * 64 + t * 16 + quad * 4 + rg;
            if (kc > qr) accs[t][rg] = -1e30f;
          }
      }
      float mv = accs[0][0];
      #pragma unroll
      for (int t = 0; t < 4; ++t)
        #pragma unroll
        for (int rg = 0; rg < 4; ++rg) mv = fmaxf(mv, accs[t][rg]);
      mv = fmaxf(mv, __shfl_xor(mv, 16));
      mv = fmaxf(mv, __shfl_xor(mv, 32));
      const float mnew = fmaxf(m_q, mv);
      const float alpha = __builtin_amdgcn_exp2f(m_q - mnew);
      float s0 = 0.0f;
      #pragma unroll
      for (int t = 0; t < 4; ++t)
        #pragma unroll
        for (int rg = 0; rg < 4; ++rg) {
          float p = __builtin_amdgcn_exp2f(accs[t][rg] - mnew);
          accs[t][rg] = p;
          s0 += p;
        }
      s0 += __shfl_xor(s0, 16);
      s0 += __shfl_xor(s0, 32);
      l_q = l_q * alpha + s0;
      m_q = mnew;

      #pragma unroll
      for (int t = 0; t < 4; ++t) {
        union { float f; unsigned u; } c0, c1, c2, c3;
        c0.f = accs[t][0]; c1.f = accs[t][1]; c2.f = accs[t][2]; c3.f = accs[t][3];
        uint2 pk;
        pk.x = ((c0.u + 0x8000u) >> 16) | ((c1.u + 0x8000u) & 0xffff0000u);
        pk.y = ((c2.u + 0x8000u) >> 16) | ((c3.u + 0x8000u) & 0xffff0000u);
        *(uint2*)&Pw[wave][r16][t * 16 + quad * 4] = pk;
      }
      float al[4];
      #pragma unroll
      for (int rg = 0; rg < 4; ++rg) al[rg] = __shfl(alpha, quad * 4 + rg);
      #pragma unroll
      for (int nt = 0; nt < 8; ++nt)
        #pragma unroll
        for (int rg = 0; rg < 4; ++rg) acco[nt][rg] *= al[rg];
      asm volatile("s_waitcnt lgkmcnt(0)" ::: "memory");
      #pragma unroll
      for (int ks2 = 0; ks2 < 2; ++ks2) {
        short8 ap = *(const short8*)&Pw[wave][r16][ks2 * 32 + quad * 8];
        #pragma unroll
        for (int nt = 0; nt < 8; ++nt) {
          short8 bv = *(const short8*)&Vt[nt * 16 + r16][ks2 * 32 + quad * 8];
          acco[nt] = MFMA_BF16(ap, bv, acco[nt]);
        }
      }
    }

    float lr[4];
    #pragma unroll
    for (int rg = 0; rg < 4; ++rg) lr[rg] = __shfl(l_q, quad * 4 + rg);
    const int sbase = qb * 64 + wave * 16 + quad * 4;
    #pragma unroll
    for (int nt = 0; nt < 8; ++nt)
      #pragma unroll
      for (int rg = 0; rg < 4; ++rg) {
        float val = acco[nt][rg] / lr[rg];
        const int row = b * S_ + sbase + rg;
        const int col = h * DH_ + nt * 16 + r16;
        O[tiled_off(row, col, D_)] = f2bf(val);  // tiled: feeds proj GEMM A
      }
  }
}

// ---------------- layernorm: y = LN(a) * g + be ----------------
// xf row-major fp32 (residual path); xb TILED bf16 (feeds FFN GEMM as A).
__global__ __launch_bounds__(256) void ln_kernel(
    const float* __restrict__ a,
    const float* __restrict__ g, const float* __restrict__ be,
    float* __restrict__ xf, u16* __restrict__ xb) {
  __shared__ float red[8];
  const int row = blockIdx.x, tid = threadIdx.x;
  float4 v = ((const float4*)(a + (size_t)row * D_))[tid];
  float s = v.x + v.y + v.z + v.w;
  float q = v.x * v.x + v.y * v.y + v.z * v.z + v.w * v.w;
  #pragma unroll
  for (int m = 1; m < 64; m <<= 1) {
    s += __shfl_xor(s, m);
    q += __shfl_xor(q, m);
  }
  const int wave = tid >> 6, lane = tid & 63;
  if (lane == 0) { red[wave] = s; red[4 + wave] = q; }
  __syncthreads();
  s = red[0] + red[1] + red[2] + red[3];
  q = red[4] + red[5] + red[6] + red[7];
  const float mu = s * (1.0f / D_);
  const float var = q * (1.0f / D_) - mu * mu;
  const float inv = rsqrtf(var + EPS_);
  const float4 gg = ((const float4*)g)[tid];
  const float4 bb = ((const float4*)be)[tid];
  float4 y;
  y.x = (v.x - mu) * inv * gg.x + bb.x;
  y.y = (v.y - mu) * inv * gg.y + bb.y;
  y.z = (v.z - mu) * inv * gg.z + bb.z;
  y.w = (v.w - mu) * inv * gg.w + bb.w;
  if (xf) ((float4*)(xf + (size_t)row * D_))[tid] = y;
  if (xb) {
    ushort4 u;
    u.x = f2bf(y.x); u.y = f2bf(y.y); u.z = f2bf(y.z); u.w = f2bf(y.w);
    *(ushort4*)(xb + tiled_off(row, tid * 4, D_)) = u;
  }
}

extern "C" void kernel_launch(void* const* d_in, const int* in_sizes, int n_in,
                              void* d_out, int out_size, void* d_ws, size_t ws_size,
                              hipStream_t stream) {
  const float* src   = (const float*)d_in[0];
  const float* w_qkv = (const float*)d_in[1];
  const float* w_out = (const float*)d_in[2];
  const float* w1    = (const float*)d_in[3];
  const float* b1    = (const float*)d_in[4];
  const float* w2    = (const float*)d_in[5];
  const float* b2    = (const float*)d_in[6];
  const float* g1    = (const float*)d_in[7];
  const float* be1   = (const float*)d_in[8];
  const float* g2    = (const float*)d_in[9];
  const float* be2   = (const float*)d_in[10];
  float* out = (float*)d_out;

  char* ws = (char*)d_ws;
  size_t off = 0;
  auto alloc = [&](size_t bytes) -> void* {
    void* p = ws + off;
    off += (bytes + 255) & ~(size_t)255;
    return p;
  };
  u16* src_bf = (u16*)alloc((size_t)ROWS_ * D_ * 2);    // tiled
  u16* wqkvT  = (u16*)alloc((size_t)3 * D_ * D_ * 2);   // tiled [3072][1024]
  u16* woutT  = (u16*)alloc((size_t)D_ * D_ * 2);       // tiled
  u16* w1T    = (u16*)alloc((size_t)DFF_ * D_ * 2);     // tiled [4096][1024]
  u16* w2T    = (u16*)alloc((size_t)D_ * DFF_ * 2);     // tiled [1024][4096]
  u16* qbuf   = (u16*)alloc((size_t)ROWS_ * D_ * 2);    // [b,h,s,dh]
  u16* kbuf   = (u16*)alloc((size_t)ROWS_ * D_ * 2);    // [b,h,s,dh]
  u16* vbuf   = (u16*)alloc((size_t)ROWS_ * D_ * 2);    // [b,h,s,dh]
  u16* obuf   = (u16*)alloc((size_t)ROWS_ * D_ * 2);    // tiled
  u16* vT     = (u16*)alloc((size_t)ROWS_ * D_ * 2);    // [b,h,dh,s]
  float* proj = (float*)alloc((size_t)ROWS_ * D_ * 4);  // row-major fp32
  float* xf   = (float*)alloc((size_t)ROWS_ * D_ * 4);  // row-major fp32
  u16* xb     = (u16*)alloc((size_t)ROWS_ * D_ * 2);    // tiled
  u16* h1     = qbuf;   // alias: q,k,v,o dead before GEMM3 writes (tiled, 67MB)
  float* ff   = proj;   // alias: proj dead after LN1

  cast_tiled_kernel<<<ROWS_ * D_ / 4 / 256, 256, 0, stream>>>(src, src_bf);
  transpose_cast_kernel<<<dim3(D_ / 32, 3 * D_ / 32), 256, 0, stream>>>(w_qkv, wqkvT, D_, 3 * D_);
  transpose_cast_kernel<<<dim3(D_ / 32, D_ / 32), 256, 0, stream>>>(w_out, woutT, D_, D_);
  transpose_cast_kernel<<<dim3(D_ / 32, DFF_ / 32), 256, 0, stream>>>(w1, w1T, D_, DFF_);
  transpose_cast_kernel<<<dim3(DFF_ / 32, D_ / 32), 256, 0, stream>>>(w2, w2T, DFF_, D_);

  // qkv = src @ w_qkv -> q,k,v [b,h,s,dh]
  gemm_kernel<0, 1024><<<dim3(ROWS_ / 128, 3 * D_ / 128), 256, 0, stream>>>(
      src_bf, wqkvT, ROWS_, 3 * D_, nullptr, nullptr, nullptr, nullptr, qbuf, kbuf, vbuf);
  transpose_v_kernel<<<dim3(S_ / 32, DH_ / 32, B_ * H_), 256, 0, stream>>>(vbuf, vT);
  attn_kernel<<<dim3(16, B_ * H_), 256, 0, stream>>>(qbuf, kbuf, vT, obuf);
  // proj = o @ w_out + src (residual fused)
  gemm_kernel<1, 1024><<<dim3(ROWS_ / 128, D_ / 128), 256, 0, stream>>>(
      obuf, woutT, ROWS_, D_, proj, nullptr, nullptr, src, nullptr, nullptr, nullptr);
  // x = LN(proj) -> xf fp32 row-major, xb bf16 tiled
  ln_kernel<<<ROWS_, 256, 0, stream>>>(proj, g1, be1, xf, xb);
  // h1 = relu(x @ w1 + b1) (bf16, tiled out)
  gemm_kernel<2, 1024><<<dim3(ROWS_ / 128, DFF_ / 128), 256, 0, stream>>>(
      xb, w1T, ROWS_, DFF_, nullptr, h1, b1, nullptr, nullptr, nullptr, nullptr);
  // ff = h1 @ w2 + b2 + xf (residual fused)
  gemm_kernel<3, 4096><<<dim3(ROWS_ / 128, D_ / 128), 256, 0, stream>>>(
      h1, w2T, ROWS_, D_, ff, nullptr, b2, xf, nullptr, nullptr, nullptr);
  // out = LN(ff)
  ln_kernel<<<ROWS_, 256, 0, stream>>>(ff, g2, be2, out, nullptr);
}

// Round 5
// 557.606 us; speedup vs baseline: 1.2775x; 1.1641x over previous
//
#include <hip/hip_runtime.h>

typedef unsigned short u16;
typedef __attribute__((ext_vector_type(8))) short short8;
typedef __attribute__((ext_vector_type(4))) float float4v;

#define MFMA_BF16(a, b, c) __builtin_amdgcn_mfma_f32_16x16x32_bf16((a), (b), (c), 0, 0, 0)

#define B_ 4
#define S_ 2048
#define D_ 1024
#define H_ 8
#define DH_ 128
#define DFF_ 4096
#define EPS_ 1e-5f
#define ROWS_ (B_ * S_)   // 8192
#define CSCALE_ 0.12751672939502f  // (1/sqrt(128)) * log2(e), folded into Q

__device__ __forceinline__ u16 f2bf(float f) {
  union { float f; unsigned u; } x; x.f = f;
  unsigned r = x.u + 0x7fffu + ((x.u >> 16) & 1u);
  return (u16)(r >> 16);
}

typedef __attribute__((address_space(1))) const unsigned int guint;
typedef __attribute__((address_space(3))) unsigned int luint;
__device__ __forceinline__ void gl2lds16(const u16* g, u16* l) {
  // each lane: 16B from its own g -> wave-uniform lds base + lane*16
  __builtin_amdgcn_global_load_lds((guint*)g, (luint*)l, 16, 0, 0);
}

// ---------------- cast fp32 -> bf16 (layout preserved) ----------------
__global__ void cast_bf16_kernel(const float* __restrict__ in, u16* __restrict__ out, int n4) {
  int i = blockIdx.x * blockDim.x + threadIdx.x;
  int stride = gridDim.x * blockDim.x;
  for (; i < n4; i += stride) {
    float4 v = ((const float4*)in)[i];
    ushort4 u;
    u.x = f2bf(v.x); u.y = f2bf(v.y); u.z = f2bf(v.z); u.w = f2bf(v.w);
    ((ushort4*)out)[i] = u;
  }
}

// ---------- cast+transpose fp32 [K][N] -> bf16 [N][K] (weights) ----------
__global__ void transpose_cast_kernel(const float* __restrict__ in, u16* __restrict__ out,
                                      int K, int N) {
  __shared__ float t[32][33];
  int k0 = blockIdx.x * 32, n0 = blockIdx.y * 32;
  int tx = threadIdx.x & 31, ty = threadIdx.x >> 5;  // 32x8 threads
  #pragma unroll
  for (int i = 0; i < 4; ++i)
    t[ty + 8 * i][tx] = in[(size_t)(k0 + ty + 8 * i) * N + n0 + tx];
  __syncthreads();
  #pragma unroll
  for (int i = 0; i < 4; ++i)
    out[(size_t)(n0 + ty + 8 * i) * K + k0 + tx] = f2bf(t[tx][ty + 8 * i]);
}

// ------- transpose V bf16 [bh][S][DH] -> [bh][DH][S] (for PV B-operand) -------
__global__ void transpose_v_kernel(const u16* __restrict__ in, u16* __restrict__ out) {
  __shared__ u16 t[32][33];
  int s0 = blockIdx.x * 32, d0 = blockIdx.y * 32, bh = blockIdx.z;
  const u16* src = in + (size_t)bh * S_ * DH_;
  u16* dst = out + (size_t)bh * DH_ * S_;
  int tx = threadIdx.x & 31, ty = threadIdx.x >> 5;
  #pragma unroll
  for (int i = 0; i < 4; ++i)
    t[ty + 8 * i][tx] = src[(size_t)(s0 + ty + 8 * i) * DH_ + d0 + tx];
  __syncthreads();
  #pragma unroll
  for (int i = 0; i < 4; ++i)
    dst[(size_t)(d0 + ty + 8 * i) * S_ + s0 + tx] = t[tx][ty + 8 * i];
}

// -------- bf16 MFMA GEMM v5: C[M,N] = A[M,K] @ Bt[N,K]^T --------
// LDS-staged both operands via global_load_lds w=16, DOUBLE-buffered with ONE
// barrier per K-iter (DMA for i+1 drains at barrier i+1, a full iter later).
// LDS uses XOR chunk swizzle: 16B chunk (row, q) sits at column slot
// q ^ s(row), s(r) = (r ^ (r>>2)) & 3 -> fragment ds_read_b128 hits each 16B
// bank group exactly 2x (free) instead of 8x (2.9x stall).
// MODE 0: scatter q/k/v bf16 ([b,h,s,dh], q pre-scaled by CSCALE_);
// MODE 1: +resid, fp32; MODE 2: +bias, relu, bf16; MODE 3: +bias+resid, fp32.
template <int MODE, int KT>
__global__ __launch_bounds__(256) void gemm_kernel(
    const u16* __restrict__ A, const u16* __restrict__ Bt,
    const int M, const int N,
    float* __restrict__ outF, u16* __restrict__ outH, const float* __restrict__ bias,
    const float* __restrict__ resid,
    u16* __restrict__ qo, u16* __restrict__ ko, u16* __restrict__ vo) {
  __shared__ u16 As[2][128][32];  // 16 KB
  __shared__ u16 Bs[2][128][32];  // 16 KB
  const int tid = threadIdx.x;
  const int lane = tid & 63, wave = tid >> 6;
  const int quad = lane >> 4, r16 = lane & 15;
  const int wm = (wave >> 1) * 64, wn = (wave & 1) * 64;
  const int m0 = blockIdx.x * 128, n0 = blockIdx.y * 128;
  constexpr int K = KT, niter = KT >> 5;

  float4v acc[4][4];
  #pragma unroll
  for (int i = 0; i < 4; ++i)
    #pragma unroll
    for (int j = 0; j < 4; ++j) acc[i][j] = (float4v)0.0f;

  // DMA: wave w covers rows [32w,32w+32) as 2 chunks of 16 rows; lane i ->
  // row i/4, LDS slot i%4; the GLOBAL chunk fetched is slot ^ s(row) so the
  // swizzled LDS layout holds chunk q at slot q ^ s(row).
  const int drow = lane >> 2;                         // 0..15 within chunk
  const int dchunk = (lane & 3) ^ ((drow ^ (drow >> 2)) & 3);
  const u16* Ag0 = A + (size_t)(m0 + wave * 32 + drow) * K + dchunk * 8;
  const u16* Ag1 = Ag0 + (size_t)16 * K;
  const u16* Bg0 = Bt + (size_t)(n0 + wave * 32 + drow) * K + dchunk * 8;
  const u16* Bg1 = Bg0 + (size_t)16 * K;
  u16* Al0 = &As[0][wave * 32][0];
  u16* Al1 = &As[0][wave * 32 + 16][0];
  u16* Bl0 = &Bs[0][wave * 32][0];
  u16* Bl1 = &Bs[0][wave * 32 + 16][0];
  constexpr int bufStep = 128 * 32;  // u16 elems per buffer

  // fragment read: row = wX + t*16 + r16, chunk quad at slot quad ^ s(r16)
  const int fcol = (quad ^ ((r16 ^ (r16 >> 2)) & 3)) * 8;

  // prologue: DMA tile 0 -> buf 0
  gl2lds16(Ag0, Al0);
  gl2lds16(Ag1, Al1);
  gl2lds16(Bg0, Bl0);
  gl2lds16(Bg1, Bl1);

  #pragma unroll 2
  for (int i = 0; i < niter; ++i) {
    __syncthreads();  // drains DMA(i) [in flight one full iter]; fences buf[(i+1)&1] readers
    if (i + 1 < niter) {
      const int k1 = (i + 1) << 5;
      const int bo = ((i + 1) & 1) ? bufStep : 0;
      gl2lds16(Ag0 + k1, Al0 + bo);
      gl2lds16(Ag1 + k1, Al1 + bo);
      gl2lds16(Bg0 + k1, Bl0 + bo);
      gl2lds16(Bg1 + k1, Bl1 + bo);
    }
    const u16* ab = &As[i & 1][0][0];
    const u16* bb = &Bs[i & 1][0][0];
    short8 af[4], bfv[4];
    #pragma unroll
    for (int t = 0; t < 4; ++t)
      af[t] = *(const short8*)(ab + ((wm + t * 16 + r16) << 5) + fcol);
    #pragma unroll
    for (int t = 0; t < 4; ++t)
      bfv[t] = *(const short8*)(bb + ((wn + t * 16 + r16) << 5) + fcol);
    #pragma unroll
    for (int ii = 0; ii < 4; ++ii)
      #pragma unroll
      for (int j = 0; j < 4; ++j) acc[ii][j] = MFMA_BF16(af[ii], bfv[j], acc[ii][j]);
  }

  // epilogue: D row = quad*4+reg, col = r16 within each 16x16 tile
  #pragma unroll
  for (int i = 0; i < 4; ++i) {
    const int rowb = m0 + wm + i * 16 + quad * 4;
    #pragma unroll
    for (int j = 0; j < 4; ++j) {
      const int col = n0 + wn + j * 16 + r16;
      #pragma unroll
      for (int rg = 0; rg < 4; ++rg) {
        float val = acc[i][j][rg];
        const int r = rowb + rg;
        if (MODE == 0) {
          const int part = col >> 10, cc = col & 1023;
          const int h = cc >> 7, dh = cc & 127;
          const int b = r >> 11, s = r & 2047;
          u16* dst = (part == 0) ? qo : (part == 1) ? ko : vo;
          if (part == 0) val *= CSCALE_;  // fold softmax scale*log2e into Q
          dst[((size_t)(b * H_ + h) * S_ + s) * DH_ + dh] = f2bf(val);
        } else if (MODE == 1) {
          val += resid[(size_t)r * N + col];  // + src residual
          outF[(size_t)r * N + col] = val;
        } else if (MODE == 2) {
          val += bias[col];
          val = fmaxf(val, 0.0f);
          outH[(size_t)r * N + col] = f2bf(val);
        } else {
          val += bias[col] + resid[(size_t)r * N + col];  // + xf residual
          outF[(size_t)r * N + col] = val;
        }
      }
    }
  }
}

// ---------------- flash causal attention (S^T formulation) ----------------
__global__ __launch_bounds__(256) void attn_kernel(
    const u16* __restrict__ Q, const u16* __restrict__ Kg,
    const u16* __restrict__ Vtg, u16* __restrict__ O) {
  __shared__ u16 Ks[64][136];     // [key][d]
  __shared__ u16 Vt[128][72];     // [d][key]
  __shared__ u16 Pw[4][16][72];   // per-wave P [q][key]
  const int tid = threadIdx.x;
  const int lane = tid & 63, wave = tid >> 6;
  const int quad = lane >> 4, r16 = lane & 15;
  const int pairIdx = blockIdx.x;  // 0..15
  const int bh = blockIdx.y;       // 0..31
  const size_t base = (size_t)bh * S_ * DH_;
  const size_t vtb = (size_t)bh * DH_ * S_;
  const int b = bh >> 3, h = bh & 7;

  const u16* kg0 = Kg + base + (size_t)(tid >> 4) * DH_ + (tid & 15) * 8;
  u16* ksl = &Ks[tid >> 4][(tid & 15) * 8];
  const u16* vg0 = Vtg + vtb + (size_t)(tid >> 3) * S_ + (tid & 7) * 8;
  u16* vtl = &Vt[tid >> 3][(tid & 7) * 8];

  for (int half = 0; half < 2; ++half) {
    const int qb = (half == 0) ? pairIdx : 31 - pairIdx;
    const int qr = qb * 64 + wave * 16 + r16;

    short8 aq[4];
    #pragma unroll
    for (int ks = 0; ks < 4; ++ks)
      aq[ks] = *(const short8*)(Q + base + (size_t)qr * DH_ + ks * 32 + quad * 8);

    float4v acco[8];
    #pragma unroll
    for (int i = 0; i < 8; ++i) acco[i] = (float4v)0.0f;
    float m_q = -1e30f, l_q = 0.0f;

    for (int kb = 0; kb <= qb; ++kb) {
      __syncthreads();
      #pragma unroll
      for (int i = 0; i < 4; ++i)
        *(short8*)(ksl + i * 16 * 136) =
            *(const short8*)(kg0 + (size_t)(kb * 64 + i * 16) * DH_);
      #pragma unroll
      for (int i = 0; i < 4; ++i)
        *(short8*)(vtl + i * 32 * 72) =
            *(const short8*)(vg0 + (size_t)i * 32 * S_ + kb * 64);
      __syncthreads();

      float4v accs[4];
      #pragma unroll
      for (int t = 0; t < 4; ++t) accs[t] = (float4v)0.0f;
      #pragma unroll
      for (int ks = 0; ks < 4; ++ks) {
        #pragma unroll
        for (int t = 0; t < 4; ++t) {
          short8 ak = *(const short8*)&Ks[t * 16 + r16][ks * 32 + quad * 8];
          accs[t] = MFMA_BF16(ak, aq[ks], accs[t]);
        }
      }
      if (kb == qb) {
        #pragma unroll
        for (int t = 0; t < 4; ++t)
          #pragma unroll
          for (int rg = 0; rg < 4; ++rg) {
            int kc = kb * 64 + t * 16 + quad * 4 + rg;
            if (kc > qr) accs[t][rg] = -1e30f;
          }
      }
      float mv = accs[0][0];
      #pragma unroll
      for (int t = 0; t < 4; ++t)
        #pragma unroll
        for (int rg = 0; rg < 4; ++rg) mv = fmaxf(mv, accs[t][rg]);
      mv = fmaxf(mv, __shfl_xor(mv, 16));
      mv = fmaxf(mv, __shfl_xor(mv, 32));
      const float mnew = fmaxf(m_q, mv);
      const float alpha = __builtin_amdgcn_exp2f(m_q - mnew);
      float s0 = 0.0f;
      #pragma unroll
      for (int t = 0; t < 4; ++t)
        #pragma unroll
        for (int rg = 0; rg < 4; ++rg) {
          float p = __builtin_amdgcn_exp2f(accs[t][rg] - mnew);
          accs[t][rg] = p;
          s0 += p;
        }
      s0 += __shfl_xor(s0, 16);
      s0 += __shfl_xor(s0, 32);
      l_q = l_q * alpha + s0;
      m_q = mnew;

      #pragma unroll
      for (int t = 0; t < 4; ++t) {
        union { float f; unsigned u; } c0, c1, c2, c3;
        c0.f = accs[t][0]; c1.f = accs[t][1]; c2.f = accs[t][2]; c3.f = accs[t][3];
        uint2 pk;
        pk.x = ((c0.u + 0x8000u) >> 16) | ((c1.u + 0x8000u) & 0xffff0000u);
        pk.y = ((c2.u + 0x8000u) >> 16) | ((c3.u + 0x8000u) & 0xffff0000u);
        *(uint2*)&Pw[wave][r16][t * 16 + quad * 4] = pk;
      }
      float al[4];
      #pragma unroll
      for (int rg = 0; rg < 4; ++rg) al[rg] = __shfl(alpha, quad * 4 + rg);
      #pragma unroll
      for (int nt = 0; nt < 8; ++nt)
        #pragma unroll
        for (int rg = 0; rg < 4; ++rg) acco[nt][rg] *= al[rg];
      asm volatile("s_waitcnt lgkmcnt(0)" ::: "memory");
      #pragma unroll
      for (int ks2 = 0; ks2 < 2; ++ks2) {
        short8 ap = *(const short8*)&Pw[wave][r16][ks2 * 32 + quad * 8];
        #pragma unroll
        for (int nt = 0; nt < 8; ++nt) {
          short8 bv = *(const short8*)&Vt[nt * 16 + r16][ks2 * 32 + quad * 8];
          acco[nt] = MFMA_BF16(ap, bv, acco[nt]);
        }
      }
    }

    float lr[4];
    #pragma unroll
    for (int rg = 0; rg < 4; ++rg) lr[rg] = __shfl(l_q, quad * 4 + rg);
    const int sbase = qb * 64 + wave * 16 + quad * 4;
    #pragma unroll
    for (int nt = 0; nt < 8; ++nt)
      #pragma unroll
      for (int rg = 0; rg < 4; ++rg) {
        float val = acco[nt][rg] / lr[rg];
        O[((size_t)(b * S_ + sbase + rg)) * D_ + h * DH_ + nt * 16 + r16] = f2bf(val);
      }
  }
}

// ---------------- layernorm: y = LN(a) * g + be ----------------
__global__ __launch_bounds__(256) void ln_kernel(
    const float* __restrict__ a,
    const float* __restrict__ g, const float* __restrict__ be,
    float* __restrict__ xf, u16* __restrict__ xb) {
  __shared__ float red[8];
  const int row = blockIdx.x, tid = threadIdx.x;
  float4 v = ((const float4*)(a + (size_t)row * D_))[tid];
  float s = v.x + v.y + v.z + v.w;
  float q = v.x * v.x + v.y * v.y + v.z * v.z + v.w * v.w;
  #pragma unroll
  for (int m = 1; m < 64; m <<= 1) {
    s += __shfl_xor(s, m);
    q += __shfl_xor(q, m);
  }
  const int wave = tid >> 6, lane = tid & 63;
  if (lane == 0) { red[wave] = s; red[4 + wave] = q; }
  __syncthreads();
  s = red[0] + red[1] + red[2] + red[3];
  q = red[4] + red[5] + red[6] + red[7];
  const float mu = s * (1.0f / D_);
  const float var = q * (1.0f / D_) - mu * mu;
  const float inv = rsqrtf(var + EPS_);
  const float4 gg = ((const float4*)g)[tid];
  const float4 bb = ((const float4*)be)[tid];
  float4 y;
  y.x = (v.x - mu) * inv * gg.x + bb.x;
  y.y = (v.y - mu) * inv * gg.y + bb.y;
  y.z = (v.z - mu) * inv * gg.z + bb.z;
  y.w = (v.w - mu) * inv * gg.w + bb.w;
  if (xf) ((float4*)(xf + (size_t)row * D_))[tid] = y;
  if (xb) {
    ushort4 u;
    u.x = f2bf(y.x); u.y = f2bf(y.y); u.z = f2bf(y.z); u.w = f2bf(y.w);
    ((ushort4*)(xb + (size_t)row * D_))[tid] = u;
  }
}

extern "C" void kernel_launch(void* const* d_in, const int* in_sizes, int n_in,
                              void* d_out, int out_size, void* d_ws, size_t ws_size,
                              hipStream_t stream) {
  const float* src   = (const float*)d_in[0];
  const float* w_qkv = (const float*)d_in[1];
  const float* w_out = (const float*)d_in[2];
  const float* w1    = (const float*)d_in[3];
  const float* b1    = (const float*)d_in[4];
  const float* w2    = (const float*)d_in[5];
  const float* b2    = (const float*)d_in[6];
  const float* g1    = (const float*)d_in[7];
  const float* be1   = (const float*)d_in[8];
  const float* g2    = (const float*)d_in[9];
  const float* be2   = (const float*)d_in[10];
  float* out = (float*)d_out;

  char* ws = (char*)d_ws;
  size_t off = 0;
  auto alloc = [&](size_t bytes) -> void* {
    void* p = ws + off;
    off += (bytes + 255) & ~(size_t)255;
    return p;
  };
  u16* src_bf = (u16*)alloc((size_t)ROWS_ * D_ * 2);    // row-major [8192][1024]
  u16* wqkvT  = (u16*)alloc((size_t)3 * D_ * D_ * 2);   // [3072][1024]
  u16* woutT  = (u16*)alloc((size_t)D_ * D_ * 2);       // [1024][1024]
  u16* w1T    = (u16*)alloc((size_t)DFF_ * D_ * 2);     // [4096][1024]
  u16* w2T    = (u16*)alloc((size_t)D_ * DFF_ * 2);     // [1024][4096]
  u16* qbuf   = (u16*)alloc((size_t)ROWS_ * D_ * 2);    // [b,h,s,dh]
  u16* kbuf   = (u16*)alloc((size_t)ROWS_ * D_ * 2);    // [b,h,s,dh]
  u16* vbuf   = (u16*)alloc((size_t)ROWS_ * D_ * 2);    // [b,h,s,dh]
  u16* obuf   = (u16*)alloc((size_t)ROWS_ * D_ * 2);    // [b,s,d] row-major
  u16* vT     = (u16*)alloc((size_t)ROWS_ * D_ * 2);    // [b,h,dh,s]
  float* proj = (float*)alloc((size_t)ROWS_ * D_ * 4);  // row-major fp32
  float* xf   = (float*)alloc((size_t)ROWS_ * D_ * 4);  // row-major fp32
  u16* xb     = (u16*)alloc((size_t)ROWS_ * D_ * 2);    // row-major bf16
  u16* h1     = qbuf;   // alias: q,k,v,o dead before GEMM3 writes
  float* ff   = proj;   // alias: proj dead after LN1

  cast_bf16_kernel<<<2048, 256, 0, stream>>>(src, src_bf, ROWS_ * D_ / 4);
  transpose_cast_kernel<<<dim3(D_ / 32, 3 * D_ / 32), 256, 0, stream>>>(w_qkv, wqkvT, D_, 3 * D_);
  transpose_cast_kernel<<<dim3(D_ / 32, D_ / 32), 256, 0, stream>>>(w_out, woutT, D_, D_);
  transpose_cast_kernel<<<dim3(D_ / 32, DFF_ / 32), 256, 0, stream>>>(w1, w1T, D_, DFF_);
  transpose_cast_kernel<<<dim3(DFF_ / 32, D_ / 32), 256, 0, stream>>>(w2, w2T, DFF_, D_);

  // qkv = src @ w_qkv -> q,k,v [b,h,s,dh]
  gemm_kernel<0, 1024><<<dim3(ROWS_ / 128, 3 * D_ / 128), 256, 0, stream>>>(
      src_bf, wqkvT, ROWS_, 3 * D_, nullptr, nullptr, nullptr, nullptr, qbuf, kbuf, vbuf);
  transpose_v_kernel<<<dim3(S_ / 32, DH_ / 32, B_ * H_), 256, 0, stream>>>(vbuf, vT);
  attn_kernel<<<dim3(16, B_ * H_), 256, 0, stream>>>(qbuf, kbuf, vT, obuf);
  // proj = o @ w_out + src (residual fused)
  gemm_kernel<1, 1024><<<dim3(ROWS_ / 128, D_ / 128), 256, 0, stream>>>(
      obuf, woutT, ROWS_, D_, proj, nullptr, nullptr, src, nullptr, nullptr, nullptr);
  // x = LN(proj) -> xf fp32, xb bf16
  ln_kernel<<<ROWS_, 256, 0, stream>>>(proj, g1, be1, xf, xb);
  // h1 = relu(x @ w1 + b1) (bf16)
  gemm_kernel<2, 1024><<<dim3(ROWS_ / 128, DFF_ / 128), 256, 0, stream>>>(
      xb, w1T, ROWS_, DFF_, nullptr, h1, b1, nullptr, nullptr, nullptr, nullptr);
  // ff = h1 @ w2 + b2 + xf (residual fused)
  gemm_kernel<3, 4096><<<dim3(ROWS_ / 128, D_ / 128), 256, 0, stream>>>(
      h1, w2T, ROWS_, D_, ff, nullptr, b2, xf, nullptr, nullptr, nullptr);
  // out = LN(ff)
  ln_kernel<<<ROWS_, 256, 0, stream>>>(ff, g2, be2, out, nullptr);
}

// Round 6
// 555.066 us; speedup vs baseline: 1.2834x; 1.0046x over previous
//
#include <hip/hip_runtime.h>

typedef unsigned short u16;
typedef __attribute__((ext_vector_type(8))) short short8;
typedef __attribute__((ext_vector_type(4))) float float4v;

#define MFMA_BF16(a, b, c) __builtin_amdgcn_mfma_f32_16x16x32_bf16((a), (b), (c), 0, 0, 0)

#define B_ 4
#define S_ 2048
#define D_ 1024
#define H_ 8
#define DH_ 128
#define DFF_ 4096
#define EPS_ 1e-5f
#define ROWS_ (B_ * S_)   // 8192
#define CSCALE_ 0.12751672939502f  // (1/sqrt(128)) * log2(e), folded into Q

__device__ __forceinline__ u16 f2bf(float f) {
  union { float f; unsigned u; } x; x.f = f;
  unsigned r = x.u + 0x7fffu + ((x.u >> 16) & 1u);
  return (u16)(r >> 16);
}

typedef __attribute__((address_space(1))) const unsigned int guint;
typedef __attribute__((address_space(3))) unsigned int luint;
__device__ __forceinline__ void gl2lds16(const u16* g, u16* l) {
  // each lane: 16B from its own g -> wave-uniform lds base + lane*16
  __builtin_amdgcn_global_load_lds((guint*)g, (luint*)l, 16, 0, 0);
}

// Tiled fragment-major layout for GEMM *A* operands: (row, k) lives in 128x32
// tiles, each tile 4096 elems (8 KB) contiguous. A wave's A-fragment load is
// then ONE coalesced 1 KB global_load_dwordx4 straight to registers.
__device__ __forceinline__ size_t tiled_off(int row, int k, int Kdim) {
  return ((size_t)(row >> 7) * (Kdim >> 5) + (k >> 5)) * 4096 +
         (size_t)((row & 127) << 5) + (k & 31);
}

// ---------------- cast fp32 row-major -> bf16 tiled (src) ----------------
__global__ void cast_tiled_kernel(const float* __restrict__ in, u16* __restrict__ out) {
  int idx = blockIdx.x * 256 + threadIdx.x;
  int g = idx * 4;
  int m = g >> 10, k = g & 1023;  // D_ = 1024
  float4 v = *(const float4*)(in + (size_t)g);
  ushort4 u;
  u.x = f2bf(v.x); u.y = f2bf(v.y); u.z = f2bf(v.z); u.w = f2bf(v.w);
  *(ushort4*)(out + tiled_off(m, k, D_)) = u;
}

// ---------- cast+transpose fp32 [K][N] -> bf16 [N][K] row-major (weights, B-side) ----------
__global__ void transpose_cast_kernel(const float* __restrict__ in, u16* __restrict__ out,
                                      int K, int N) {
  __shared__ float t[32][33];
  int k0 = blockIdx.x * 32, n0 = blockIdx.y * 32;
  int tx = threadIdx.x & 31, ty = threadIdx.x >> 5;  // 32x8 threads
  #pragma unroll
  for (int i = 0; i < 4; ++i)
    t[ty + 8 * i][tx] = in[(size_t)(k0 + ty + 8 * i) * N + n0 + tx];
  __syncthreads();
  #pragma unroll
  for (int i = 0; i < 4; ++i)
    out[(size_t)(n0 + ty + 8 * i) * K + k0 + tx] = f2bf(t[tx][ty + 8 * i]);
}

// ------- transpose V bf16 [bh][S][DH] -> [bh][DH][S] (for PV B-operand) -------
__global__ void transpose_v_kernel(const u16* __restrict__ in, u16* __restrict__ out) {
  __shared__ u16 t[32][33];
  int s0 = blockIdx.x * 32, d0 = blockIdx.y * 32, bh = blockIdx.z;
  const u16* src = in + (size_t)bh * S_ * DH_;
  u16* dst = out + (size_t)bh * DH_ * S_;
  int tx = threadIdx.x & 31, ty = threadIdx.x >> 5;
  #pragma unroll
  for (int i = 0; i < 4; ++i)
    t[ty + 8 * i][tx] = src[(size_t)(s0 + ty + 8 * i) * DH_ + d0 + tx];
  __syncthreads();
  #pragma unroll
  for (int i = 0; i < 4; ++i)
    dst[(size_t)(d0 + ty + 8 * i) * S_ + s0 + tx] = t[tx][ty + 8 * i];
}

// ---- bf16 MFMA GEMM v6 (hybrid flatmm): C[M,N] = A[M,K] @ Bt[N,K]^T ----
// A TILED global -> registers (1-iter dbuf, coalesced 1 KB loads, pipelined by
// compiler vmcnt, decoupled from barriers). B row-major -> LDS via
// global_load_lds, double-buffered, ONE barrier per K-iter. Halves LDS pipe
// traffic and DMA drain vs all-LDS staging.
// MODE 0: scatter q/k/v bf16 ([b,h,s,dh], q pre-scaled by CSCALE_);
// MODE 1: +resid, fp32 row-major; MODE 2: +bias, relu, bf16 TILED (feeds
// FFN2 as A); MODE 3: +bias+resid, fp32 row-major.
template <int MODE, int KT>
__global__ __launch_bounds__(256) void gemm_kernel(
    const u16* __restrict__ A, const u16* __restrict__ Bt,
    const int M, const int N,
    float* __restrict__ outF, u16* __restrict__ outH, const float* __restrict__ bias,
    const float* __restrict__ resid,
    u16* __restrict__ qo, u16* __restrict__ ko, u16* __restrict__ vo) {
  __shared__ u16 Bs[2][128][32];  // 16 KB
  const int tid = threadIdx.x;
  const int lane = tid & 63, wave = tid >> 6;
  const int quad = lane >> 4, r16 = lane & 15;
  const int wm = (wave >> 1) * 64, wn = (wave & 1) * 64;
  const int m0 = blockIdx.x * 128, n0 = blockIdx.y * 128;
  constexpr int K = KT, niter = KT >> 5;

  float4v acc[4][4];
  #pragma unroll
  for (int i = 0; i < 4; ++i)
    #pragma unroll
    for (int j = 0; j < 4; ++j) acc[i][j] = (float4v)0.0f;

  // B DMA: wave w covers rows [32w,32w+32) as 2 chunks of 16 rows;
  // lane -> row lane/4, 16B segment lane%4.
  const int drow = lane >> 2, dseg = lane & 3;
  const u16* Bg0 = Bt + (size_t)(n0 + wave * 32 + drow) * K + dseg * 8;
  const u16* Bg1 = Bg0 + (size_t)16 * K;
  u16* Bl0 = &Bs[0][wave * 32][0];
  u16* Bl1 = &Bs[0][wave * 32 + 16][0];
  constexpr int bufStep = 128 * 32;  // u16 elems per buffer

  // A fragment pointers (tiled): lane covers rows wm + t*16 + r16, k seg quad*8
  const u16* ap[4];
  #pragma unroll
  for (int t = 0; t < 4; ++t)
    ap[t] = A + (size_t)(m0 >> 7) * niter * 4096 +
            (size_t)((wm + t * 16 + r16) << 5) + quad * 8;

  // prologue: B tile 0 -> buf 0; A frags for tile 0 -> registers
  gl2lds16(Bg0, Bl0);
  gl2lds16(Bg1, Bl1);
  short8 a_cur[4], a_nxt[4];
  #pragma unroll
  for (int t = 0; t < 4; ++t) a_cur[t] = *(const short8*)(ap[t]);

  #pragma unroll 2
  for (int i = 0; i < niter; ++i) {
    __syncthreads();  // drains B-DMA(i) (in flight since iter i-1); fences readers of other buf
    if (i + 1 < niter) {
      const int k1 = (i + 1) << 5;
      const int bo = ((i + 1) & 1) ? bufStep : 0;
      gl2lds16(Bg0 + k1, Bl0 + bo);
      gl2lds16(Bg1 + k1, Bl1 + bo);
      const size_t o = (size_t)(i + 1) * 4096;
      #pragma unroll
      for (int t = 0; t < 4; ++t) a_nxt[t] = *(const short8*)(ap[t] + o);
    }
    short8 bfv[4];
    #pragma unroll
    for (int t = 0; t < 4; ++t)
      bfv[t] = *(const short8*)&Bs[i & 1][wn + t * 16 + r16][quad * 8];
    #pragma unroll
    for (int ii = 0; ii < 4; ++ii)
      #pragma unroll
      for (int j = 0; j < 4; ++j) acc[ii][j] = MFMA_BF16(a_cur[ii], bfv[j], acc[ii][j]);
    #pragma unroll
    for (int t = 0; t < 4; ++t) a_cur[t] = a_nxt[t];
  }

  // epilogue: D row = quad*4+reg, col = r16 within each 16x16 tile
  #pragma unroll
  for (int i = 0; i < 4; ++i) {
    const int rowb = m0 + wm + i * 16 + quad * 4;
    #pragma unroll
    for (int j = 0; j < 4; ++j) {
      const int col = n0 + wn + j * 16 + r16;
      #pragma unroll
      for (int rg = 0; rg < 4; ++rg) {
        float val = acc[i][j][rg];
        const int r = rowb + rg;
        if (MODE == 0) {
          const int part = col >> 10, cc = col & 1023;
          const int h = cc >> 7, dh = cc & 127;
          const int b = r >> 11, s = r & 2047;
          u16* dst = (part == 0) ? qo : (part == 1) ? ko : vo;
          if (part == 0) val *= CSCALE_;  // fold softmax scale*log2e into Q
          dst[((size_t)(b * H_ + h) * S_ + s) * DH_ + dh] = f2bf(val);
        } else if (MODE == 1) {
          val += resid[(size_t)r * N + col];  // + src residual
          outF[(size_t)r * N + col] = val;
        } else if (MODE == 2) {
          val += bias[col];
          val = fmaxf(val, 0.0f);
          outH[tiled_off(r, col, N)] = f2bf(val);  // tiled: feeds FFN2 A
        } else {
          val += bias[col] + resid[(size_t)r * N + col];  // + xf residual
          outF[(size_t)r * N + col] = val;
        }
      }
    }
  }
}

// ---------------- flash causal attention (S^T formulation) ----------------
// O written TILED (feeds proj GEMM as A operand).
__global__ __launch_bounds__(256) void attn_kernel(
    const u16* __restrict__ Q, const u16* __restrict__ Kg,
    const u16* __restrict__ Vtg, u16* __restrict__ O) {
  __shared__ u16 Ks[64][136];     // [key][d]
  __shared__ u16 Vt[128][72];     // [d][key]
  __shared__ u16 Pw[4][16][72];   // per-wave P [q][key]
  const int tid = threadIdx.x;
  const int lane = tid & 63, wave = tid >> 6;
  const int quad = lane >> 4, r16 = lane & 15;
  const int pairIdx = blockIdx.x;  // 0..15
  const int bh = blockIdx.y;       // 0..31
  const size_t base = (size_t)bh * S_ * DH_;
  const size_t vtb = (size_t)bh * DH_ * S_;
  const int b = bh >> 3, h = bh & 7;

  const u16* kg0 = Kg + base + (size_t)(tid >> 4) * DH_ + (tid & 15) * 8;
  u16* ksl = &Ks[tid >> 4][(tid & 15) * 8];
  const u16* vg0 = Vtg + vtb + (size_t)(tid >> 3) * S_ + (tid & 7) * 8;
  u16* vtl = &Vt[tid >> 3][(tid & 7) * 8];

  for (int half = 0; half < 2; ++half) {
    const int qb = (half == 0) ? pairIdx : 31 - pairIdx;
    const int qr = qb * 64 + wave * 16 + r16;

    short8 aq[4];
    #pragma unroll
    for (int ks = 0; ks < 4; ++ks)
      aq[ks] = *(const short8*)(Q + base + (size_t)qr * DH_ + ks * 32 + quad * 8);

    float4v acco[8];
    #pragma unroll
    for (int i = 0; i < 8; ++i) acco[i] = (float4v)0.0f;
    float m_q = -1e30f, l_q = 0.0f;

    for (int kb = 0; kb <= qb; ++kb) {
      __syncthreads();
      #pragma unroll
      for (int i = 0; i < 4; ++i)
        *(short8*)(ksl + i * 16 * 136) =
            *(const short8*)(kg0 + (size_t)(kb * 64 + i * 16) * DH_);
      #pragma unroll
      for (int i = 0; i < 4; ++i)
        *(short8*)(vtl + i * 32 * 72) =
            *(const short8*)(vg0 + (size_t)i * 32 * S_ + kb * 64);
      __syncthreads();

      float4v accs[4];
      #pragma unroll
      for (int t = 0; t < 4; ++t) accs[t] = (float4v)0.0f;
      #pragma unroll
      for (int ks = 0; ks < 4; ++ks) {
        #pragma unroll
        for (int t = 0; t < 4; ++t) {
          short8 ak = *(const short8*)&Ks[t * 16 + r16][ks * 32 + quad * 8];
          accs[t] = MFMA_BF16(ak, aq[ks], accs[t]);
        }
      }
      if (kb == qb) {
        #pragma unroll
        for (int t = 0; t < 4; ++t)
          #pragma unroll
          for (int rg = 0; rg < 4; ++rg) {
            int kc = kb * 64 + t * 16 + quad * 4 + rg;
            if (kc > qr) accs[t][rg] = -1e30f;
          }
      }
      float mv = accs[0][0];
      #pragma unroll
      for (int t = 0; t < 4; ++t)
        #pragma unroll
        for (int rg = 0; rg < 4; ++rg) mv = fmaxf(mv, accs[t][rg]);
      mv = fmaxf(mv, __shfl_xor(mv, 16));
      mv = fmaxf(mv, __shfl_xor(mv, 32));
      const float mnew = fmaxf(m_q, mv);
      const float alpha = __builtin_amdgcn_exp2f(m_q - mnew);
      float s0 = 0.0f;
      #pragma unroll
      for (int t = 0; t < 4; ++t)
        #pragma unroll
        for (int rg = 0; rg < 4; ++rg) {
          float p = __builtin_amdgcn_exp2f(accs[t][rg] - mnew);
          accs[t][rg] = p;
          s0 += p;
        }
      s0 += __shfl_xor(s0, 16);
      s0 += __shfl_xor(s0, 32);
      l_q = l_q * alpha + s0;
      m_q = mnew;

      #pragma unroll
      for (int t = 0; t < 4; ++t) {
        union { float f; unsigned u; } c0, c1, c2, c3;
        c0.f = accs[t][0]; c1.f = accs[t][1]; c2.f = accs[t][2]; c3.f = accs[t][3];
        uint2 pk;
        pk.x = ((c0.u + 0x8000u) >> 16) | ((c1.u + 0x8000u) & 0xffff0000u);
        pk.y = ((c2.u + 0x8000u) >> 16) | ((c3.u + 0x8000u) & 0xffff0000u);
        *(uint2*)&Pw[wave][r16][t * 16 + quad * 4] = pk;
      }
      float al[4];
      #pragma unroll
      for (int rg = 0; rg < 4; ++rg) al[rg] = __shfl(alpha, quad * 4 + rg);
      #pragma unroll
      for (int nt = 0; nt < 8; ++nt)
        #pragma unroll
        for (int rg = 0; rg < 4; ++rg) acco[nt][rg] *= al[rg];
      asm volatile("s_waitcnt lgkmcnt(0)" ::: "memory");
      #pragma unroll
      for (int ks2 = 0; ks2 < 2; ++ks2) {
        short8 ap = *(const short8*)&Pw[wave][r16][ks2 * 32 + quad * 8];
        #pragma unroll
        for (int nt = 0; nt < 8; ++nt) {
          short8 bv = *(const short8*)&Vt[nt * 16 + r16][ks2 * 32 + quad * 8];
          acco[nt] = MFMA_BF16(ap, bv, acco[nt]);
        }
      }
    }

    float lr[4];
    #pragma unroll
    for (int rg = 0; rg < 4; ++rg) lr[rg] = __shfl(l_q, quad * 4 + rg);
    const int sbase = qb * 64 + wave * 16 + quad * 4;
    #pragma unroll
    for (int nt = 0; nt < 8; ++nt)
      #pragma unroll
      for (int rg = 0; rg < 4; ++rg) {
        float val = acco[nt][rg] / lr[rg];
        const int row = b * S_ + sbase + rg;
        const int col = h * DH_ + nt * 16 + r16;
        O[tiled_off(row, col, D_)] = f2bf(val);  // tiled: feeds proj GEMM A
      }
  }
}

// ---------------- layernorm: y = LN(a) * g + be ----------------
// xf row-major fp32 (residual path); xb TILED bf16 (feeds FFN1 as A).
__global__ __launch_bounds__(256) void ln_kernel(
    const float* __restrict__ a,
    const float* __restrict__ g, const float* __restrict__ be,
    float* __restrict__ xf, u16* __restrict__ xb) {
  __shared__ float red[8];
  const int row = blockIdx.x, tid = threadIdx.x;
  float4 v = ((const float4*)(a + (size_t)row * D_))[tid];
  float s = v.x + v.y + v.z + v.w;
  float q = v.x * v.x + v.y * v.y + v.z * v.z + v.w * v.w;
  #pragma unroll
  for (int m = 1; m < 64; m <<= 1) {
    s += __shfl_xor(s, m);
    q += __shfl_xor(q, m);
  }
  const int wave = tid >> 6, lane = tid & 63;
  if (lane == 0) { red[wave] = s; red[4 + wave] = q; }
  __syncthreads();
  s = red[0] + red[1] + red[2] + red[3];
  q = red[4] + red[5] + red[6] + red[7];
  const float mu = s * (1.0f / D_);
  const float var = q * (1.0f / D_) - mu * mu;
  const float inv = rsqrtf(var + EPS_);
  const float4 gg = ((const float4*)g)[tid];
  const float4 bb = ((const float4*)be)[tid];
  float4 y;
  y.x = (v.x - mu) * inv * gg.x + bb.x;
  y.y = (v.y - mu) * inv * gg.y + bb.y;
  y.z = (v.z - mu) * inv * gg.z + bb.z;
  y.w = (v.w - mu) * inv * gg.w + bb.w;
  if (xf) ((float4*)(xf + (size_t)row * D_))[tid] = y;
  if (xb) {
    ushort4 u;
    u.x = f2bf(y.x); u.y = f2bf(y.y); u.z = f2bf(y.z); u.w = f2bf(y.w);
    *(ushort4*)(xb + tiled_off(row, tid * 4, D_)) = u;
  }
}

extern "C" void kernel_launch(void* const* d_in, const int* in_sizes, int n_in,
                              void* d_out, int out_size, void* d_ws, size_t ws_size,
                              hipStream_t stream) {
  const float* src   = (const float*)d_in[0];
  const float* w_qkv = (const float*)d_in[1];
  const float* w_out = (const float*)d_in[2];
  const float* w1    = (const float*)d_in[3];
  const float* b1    = (const float*)d_in[4];
  const float* w2    = (const float*)d_in[5];
  const float* b2    = (const float*)d_in[6];
  const float* g1    = (const float*)d_in[7];
  const float* be1   = (const float*)d_in[8];
  const float* g2    = (const float*)d_in[9];
  const float* be2   = (const float*)d_in[10];
  float* out = (float*)d_out;

  char* ws = (char*)d_ws;
  size_t off = 0;
  auto alloc = [&](size_t bytes) -> void* {
    void* p = ws + off;
    off += (bytes + 255) & ~(size_t)255;
    return p;
  };
  u16* src_bf = (u16*)alloc((size_t)ROWS_ * D_ * 2);    // TILED (A of qkv GEMM)
  u16* wqkvT  = (u16*)alloc((size_t)3 * D_ * D_ * 2);   // row-major [3072][1024]
  u16* woutT  = (u16*)alloc((size_t)D_ * D_ * 2);       // row-major [1024][1024]
  u16* w1T    = (u16*)alloc((size_t)DFF_ * D_ * 2);     // row-major [4096][1024]
  u16* w2T    = (u16*)alloc((size_t)D_ * DFF_ * 2);     // row-major [1024][4096]
  u16* qbuf   = (u16*)alloc((size_t)ROWS_ * D_ * 2);    // [b,h,s,dh]
  u16* kbuf   = (u16*)alloc((size_t)ROWS_ * D_ * 2);    // [b,h,s,dh]
  u16* vbuf   = (u16*)alloc((size_t)ROWS_ * D_ * 2);    // [b,h,s,dh]
  u16* obuf   = (u16*)alloc((size_t)ROWS_ * D_ * 2);    // TILED (A of proj GEMM)
  u16* vT     = (u16*)alloc((size_t)ROWS_ * D_ * 2);    // [b,h,dh,s]
  float* proj = (float*)alloc((size_t)ROWS_ * D_ * 4);  // row-major fp32
  float* xf   = (float*)alloc((size_t)ROWS_ * D_ * 4);  // row-major fp32
  u16* xb     = (u16*)alloc((size_t)ROWS_ * D_ * 2);    // TILED (A of FFN1)
  u16* h1     = qbuf;   // alias: q,k,v,o dead before FFN1 writes (TILED, 64MB)
  float* ff   = proj;   // alias: proj dead after LN1

  cast_tiled_kernel<<<ROWS_ * D_ / 4 / 256, 256, 0, stream>>>(src, src_bf);
  transpose_cast_kernel<<<dim3(D_ / 32, 3 * D_ / 32), 256, 0, stream>>>(w_qkv, wqkvT, D_, 3 * D_);
  transpose_cast_kernel<<<dim3(D_ / 32, D_ / 32), 256, 0, stream>>>(w_out, woutT, D_, D_);
  transpose_cast_kernel<<<dim3(D_ / 32, DFF_ / 32), 256, 0, stream>>>(w1, w1T, D_, DFF_);
  transpose_cast_kernel<<<dim3(DFF_ / 32, D_ / 32), 256, 0, stream>>>(w2, w2T, DFF_, D_);

  // qkv = src @ w_qkv -> q,k,v [b,h,s,dh]
  gemm_kernel<0, 1024><<<dim3(ROWS_ / 128, 3 * D_ / 128), 256, 0, stream>>>(
      src_bf, wqkvT, ROWS_, 3 * D_, nullptr, nullptr, nullptr, nullptr, qbuf, kbuf, vbuf);
  transpose_v_kernel<<<dim3(S_ / 32, DH_ / 32, B_ * H_), 256, 0, stream>>>(vbuf, vT);
  attn_kernel<<<dim3(16, B_ * H_), 256, 0, stream>>>(qbuf, kbuf, vT, obuf);
  // proj = o @ w_out + src (residual fused)
  gemm_kernel<1, 1024><<<dim3(ROWS_ / 128, D_ / 128), 256, 0, stream>>>(
      obuf, woutT, ROWS_, D_, proj, nullptr, nullptr, src, nullptr, nullptr, nullptr);
  // x = LN(proj) -> xf fp32 row-major, xb bf16 tiled
  ln_kernel<<<ROWS_, 256, 0, stream>>>(proj, g1, be1, xf, xb);
  // h1 = relu(x @ w1 + b1) (bf16, tiled out)
  gemm_kernel<2, 1024><<<dim3(ROWS_ / 128, DFF_ / 128), 256, 0, stream>>>(
      xb, w1T, ROWS_, DFF_, nullptr, h1, b1, nullptr, nullptr, nullptr, nullptr);
  // ff = h1 @ w2 + b2 + xf (residual fused)
  gemm_kernel<3, 4096><<<dim3(ROWS_ / 128, D_ / 128), 256, 0, stream>>>(
      h1, w2T, ROWS_, D_, ff, nullptr, b2, xf, nullptr, nullptr, nullptr);
  // out = LN(ff)
  ln_kernel<<<ROWS_, 256, 0, stream>>>(ff, g2, be2, out, nullptr);
}